// Round 8
// baseline (926.864 us; speedup 1.0000x reference)
//
#include <hip/hip_runtime.h>
#include <hip/hip_bf16.h>

#define BB   8
#define TT   1024
#define NCBN 2
#define DD   128
#define KK   8192
#define MM   8192          // B*T queries per codebook

constexpr int OUT_IDX_OFF  = BB * 256 * TT;                // 2097152
constexpr int OUT_LOSS_OFF = OUT_IDX_OFF + BB * NCBN * TT; // 2113536

#define THR   0.45f        // >= 2*worst-case |y_bf16 - y_f32| (bound ~0.36)
#define QCAP  1024
#define NSPL  8            // K-splits of 1024 codes

typedef __attribute__((ext_vector_type(8))) short   short8;   // 8 bf16
typedef __attribute__((ext_vector_type(4))) float   float4v;

__device__ __forceinline__ unsigned short f2bf(float v) {
    unsigned u = __float_as_uint(v);
    return (unsigned short)((u + 0x7FFFu + ((u >> 16) & 1u)) >> 16);  // RNE
}
__device__ __forceinline__ void gl_lds16(const void* g, void* l) {
    __builtin_amdgcn_global_load_lds(
        (const __attribute__((address_space(1))) unsigned int*)g,
        (__attribute__((address_space(3))) unsigned int*)l, 16, 0, 0);
}
__device__ __forceinline__ unsigned fmono(float v) {   // order-preserving u32
    unsigned u = __float_as_uint(v);
    return (u & 0x80000000u) ? ~u : (u | 0x80000000u);
}
__device__ __forceinline__ float fmono_inv(unsigned mu) {
    unsigned u = (mu & 0x80000000u) ? (mu & 0x7FFFFFFFu) : ~mu;
    return __uint_as_float(u);
}

// ---------------------------------------------------------------------------
// Prep. Blocks 0..511: pack_x 32-t tiles (transpose -> xbf bf16 rows, x2,
// x32t, pmin/gminU init). Blocks 512..575: pack_c (bf16 rows + c2) + zero
// loss + gcnt. R1 ascending-d fmaf association throughout (bit-exact).
// ---------------------------------------------------------------------------
__global__ __launch_bounds__(256)
void prep_kernel(const float* __restrict__ x, const float* __restrict__ cb,
                 unsigned short* __restrict__ xbf, unsigned short* __restrict__ cbf,
                 float* __restrict__ x2, float* __restrict__ c2,
                 float* __restrict__ x32t, int contig,
                 unsigned long long* __restrict__ pmin,
                 unsigned int* __restrict__ gminU,
                 unsigned int* __restrict__ gcnt,
                 float* __restrict__ out) {
    const int bx = blockIdx.x;
    const int tid = threadIdx.x;

    if (bx >= 512) {   // ---- pack_c
        int g = (bx - 512) * 256 + tid;   // n*K + k
        if (g == 0) out[OUT_LOSS_OFF] = 0.f;
        if (bx == 512 && tid < 128) gcnt[tid] = 0u;
        const float4* crow = (const float4*)(cb + (size_t)g * DD);
        unsigned short* orow = cbf + (size_t)g * DD;
        float s = 0.f;
#pragma unroll 4
        for (int i2 = 0; i2 < 16; ++i2) {
            float4 v0 = crow[2 * i2];
            float4 v1 = crow[2 * i2 + 1];
            s = fmaf(v0.x, v0.x, s); s = fmaf(v0.y, v0.y, s);
            s = fmaf(v0.z, v0.z, s); s = fmaf(v0.w, v0.w, s);
            s = fmaf(v1.x, v1.x, s); s = fmaf(v1.y, v1.y, s);
            s = fmaf(v1.z, v1.z, s); s = fmaf(v1.w, v1.w, s);
            uint4 pk;
            pk.x = (unsigned)f2bf(v0.x) | ((unsigned)f2bf(v0.y) << 16);
            pk.y = (unsigned)f2bf(v0.z) | ((unsigned)f2bf(v0.w) << 16);
            pk.z = (unsigned)f2bf(v1.x) | ((unsigned)f2bf(v1.y) << 16);
            pk.w = (unsigned)f2bf(v1.z) | ((unsigned)f2bf(v1.w) << 16);
            *(uint4*)(orow + i2 * 8) = pk;
        }
        c2[g] = s;
        return;
    }

    // ---- pack_x: bx = bn*32 + ttile; tile = 128 d x 32 t
    __shared__ float Ld[DD][33];
    const int bn = bx >> 5, ttile = bx & 31;
    const int b = bn >> 1, n = bn & 1;
    const int t0 = ttile * 32;

    const float* base = x + ((size_t)(b * 256 + n * 128)) * TT + t0;
    {
        int d = tid >> 1, off = (tid & 1) * 16;
        const float* rp = base + (size_t)d * TT + off;
#pragma unroll
        for (int j = 0; j < 4; ++j) {
            float4 v = *(const float4*)(rp + j * 4);
            int t = off + j * 4;
            Ld[d][t + 0] = v.x; Ld[d][t + 1] = v.y;
            Ld[d][t + 2] = v.z; Ld[d][t + 3] = v.w;
        }
    }
    __syncthreads();

    if (tid < 32) {
        float s = 0.f;
        for (int d = 0; d < DD; ++d) { float v = Ld[d][tid]; s = fmaf(v, v, s); }
        size_t gi = (size_t)n * MM + b * TT + t0 + tid;
        x2[gi] = s;
        pmin[gi] = 0xFFFFFFFFFFFFFFFFull;
        gminU[gi] = fmono(3.4e38f);
    }

    unsigned short* orow0 = xbf + ((size_t)n * MM + b * TT + t0) * DD;
#pragma unroll
    for (int pp = 0; pp < 2; ++pp) {
        int u = tid + pp * 256;            // 512 units = 32 rows x 16 segs
        int tt = u >> 4, sg = u & 15;
        unsigned short tmp[8];
#pragma unroll
        for (int j = 0; j < 8; ++j) tmp[j] = f2bf(Ld[sg * 8 + j][tt]);
        uint4 pk;
        pk.x = (unsigned)tmp[0] | ((unsigned)tmp[1] << 16);
        pk.y = (unsigned)tmp[2] | ((unsigned)tmp[3] << 16);
        pk.z = (unsigned)tmp[4] | ((unsigned)tmp[5] << 16);
        pk.w = (unsigned)tmp[6] | ((unsigned)tmp[7] << 16);
        *(uint4*)(orow0 + (size_t)tt * DD + sg * 8) = pk;
    }

    if (contig) {   // fp32 transposed copy for fast exact rescore/gather
        float* xrow0 = x32t + ((size_t)n * MM + b * TT + t0) * DD;
#pragma unroll
        for (int pp = 0; pp < 4; ++pp) {
            int u = tid + pp * 256;        // 1024 units = 32 rows x 32 f4-segs
            int tt = u >> 5, sg = u & 31;
            float4 v = { Ld[sg * 4 + 0][tt], Ld[sg * 4 + 1][tt],
                         Ld[sg * 4 + 2][tt], Ld[sg * 4 + 3][tt] };
            *(float4*)(xrow0 + (size_t)tt * DD + sg * 4) = v;
        }
    }
}

// ---------------------------------------------------------------------------
// Exact fp32 rescore: bit-identical association to the R1 passing kernel.
// atomicMin on (s_bits<<32 | k) = "min s, then lowest k" (s > 0 here).
// ---------------------------------------------------------------------------
__device__ void rescore_one(int n, int m, int k,
                            const float* __restrict__ xex, int contig,
                            const float* __restrict__ cb,
                            const float* __restrict__ x2, const float* __restrict__ c2,
                            unsigned long long* __restrict__ pmin) {
    const float* xp; int st;
    if (contig) { xp = xex + ((size_t)n * MM + m) * DD; st = 1; }
    else {
        int b = m >> 10, t = m & (TT - 1);
        xp = xex + ((size_t)(b * 256 + n * 128)) * TT + t; st = TT;
    }
    const float* cp = cb + ((size_t)(n * KK + k)) * DD;
    float xc = 0.f;
    for (int d = 0; d < DD; ++d)
        xc = fmaf(xp[(size_t)d * st], cp[d], xc);
    float u = x2[(size_t)n * MM + m] - 2.0f * xc;
    float s = u + c2[n * KK + k];
    unsigned long long pk = ((unsigned long long)__float_as_uint(s) << 32) | (unsigned)k;
    atomicMin(pmin + (size_t)n * MM + m, pk);
}

// ---------------------------------------------------------------------------
// Screen v8: SINGLE MFMA pass per slice with per-(thread,query) top-2.
// grid 1024: n=id&1, ks=(id>>1)&7, qt=id>>4. Block tile 128q x 1024c,
// 8 chunks of 128c staged in one 32-KB swizzled LDS buffer (gl_lds, R6).
// Per (thread,query): v1/c1/v2 over the thread's 128 slice-codes. Exact
// slice-min m via LDS reduce; push c1 (v1<=thr) or 16-code rescan subtasks
// (v2<=thr, provably covers argmin hidden at depth>=2). Exact fp32 drain.
// Fused gather via arrival counter (R7, proven).
// ---------------------------------------------------------------------------
__global__ __launch_bounds__(256, 3)
void screen_kernel(const unsigned short* __restrict__ xbf,
                   const unsigned short* __restrict__ cbf,
                   const float* __restrict__ c2,
                   const float* __restrict__ xex, int contig,
                   const float* __restrict__ cb32,
                   const float* __restrict__ x2,
                   unsigned int* __restrict__ gminU,
                   unsigned long long* __restrict__ pmin,
                   unsigned int* __restrict__ gcnt,
                   float* __restrict__ out) {
    __shared__ __align__(16) unsigned short Ash[128 * 128];   // 32 KB
    __shared__ float        c2s[1024];                        // 4 KB (slice c2)
    __shared__ unsigned int minU[128];
    __shared__ float        gthr[128];
    __shared__ unsigned int qcnt;
    __shared__ unsigned int queue[QCAP];                      // 4 KB
    __shared__ int          kid[128];
    __shared__ float        wred[4];
    __shared__ int          dflag;

    const int tid = threadIdx.x;
    const int id  = blockIdx.x;
    const int n   = id & 1;
    const int ks  = (id >> 1) & 7;
    const int qt  = id >> 4;           // 0..63
    const int m0  = qt * 128;
    const int k0  = ks * 1024;
    const size_t gq = (size_t)n * MM + m0;

    const int wave = tid >> 6, lane = tid & 63;
    const int cw = wave & 1, qw = wave >> 1;
    const int quad = lane >> 4, l15 = lane & 15;

    // staging map: unit i -> row=i>>4, phys seg = (i&15); logical seg XOR row
    int goff[8];
#pragma unroll
    for (int p = 0; p < 8; ++p) {
        int u   = (p * 4 + wave) * 64 + lane;
        int row = u >> 4;
        int seg = (u & 15) ^ (row & 15);
        goff[p] = (row * DD + seg * 8) * 2;
    }

    // ---- stage queries into Ash (async) + c2 slice into LDS
    {
        const char* src = (const char*)(xbf + ((size_t)n * MM + m0) * DD);
#pragma unroll
        for (int p = 0; p < 8; ++p)
            gl_lds16(src + goff[p], &Ash[(p * 4 + wave) * 512]);
    }
    *(float4*)&c2s[tid * 4] = *(const float4*)(c2 + (size_t)n * KK + k0 + tid * 4);
    if (tid < 128) minU[tid] = 0xFFFFFFFFu;
    if (tid == 0)  qcnt = 0;
    __syncthreads();

    // ---- query B-fragments (whole D=128) register-resident
    short8 bfr[4][4];                      // [tq][k4]
#pragma unroll
    for (int tq = 0; tq < 4; ++tq) {
        int q = qw * 64 + tq * 16 + l15;   // q&15 == l15
#pragma unroll
        for (int k4 = 0; k4 < 4; ++k4) {
            int seg = k4 * 4 + quad;
            bfr[tq][k4] = *(const short8*)(&Ash[q * 128 + ((seg ^ l15) * 8)]);
        }
    }

    float v1[4] = {3.4e38f, 3.4e38f, 3.4e38f, 3.4e38f};
    float v2[4] = {3.4e38f, 3.4e38f, 3.4e38f, 3.4e38f};
    unsigned c1[4] = {0, 0, 0, 0};

    const char* asrc0 = (const char*)(cbf + ((size_t)n * KK + k0) * DD);

    for (int ch = 0; ch < 8; ++ch) {
        __syncthreads();               // Ash free (bfr loaded / prev consumed)
        {
            const char* src = asrc0 + (size_t)ch * (128 * DD * 2);
#pragma unroll
            for (int p = 0; p < 8; ++p)
                gl_lds16(src + goff[p], &Ash[(p * 4 + wave) * 512]);
        }
        __syncthreads();               // Ash ready

        float4v acc[4][4];             // [tc][tq]
#pragma unroll
        for (int tc = 0; tc < 4; ++tc)
#pragma unroll
            for (int tq = 0; tq < 4; ++tq)
                acc[tc][tq] = (float4v){0.f, 0.f, 0.f, 0.f};

#pragma unroll
        for (int k4 = 0; k4 < 4; ++k4) {
            short8 a[4];
#pragma unroll
            for (int tc = 0; tc < 4; ++tc) {
                int r = cw * 64 + tc * 16 + l15;       // r&15 == l15
                int seg = k4 * 4 + quad;
                a[tc] = *(const short8*)(&Ash[r * 128 + ((seg ^ l15) * 8)]);
            }
#pragma unroll
            for (int tc = 0; tc < 4; ++tc)
#pragma unroll
                for (int tq = 0; tq < 4; ++tq)
                    acc[tc][tq] = __builtin_amdgcn_mfma_f32_16x16x32_bf16(
                        a[tc], bfr[tq][k4], acc[tc][tq], 0, 0, 0);
        }

        // epilogue: y = c2 - 2*xc; per-query top-2 update (rare insert path)
        float4v c2r4[4];
#pragma unroll
        for (int tc = 0; tc < 4; ++tc)
            c2r4[tc] = *(const float4v*)(&c2s[ch * 128 + cw * 64 + tc * 16 + quad * 4]);
#pragma unroll
        for (int tq = 0; tq < 4; ++tq) {
            float m16 = 3.4e38f;
#pragma unroll
            for (int tc = 0; tc < 4; ++tc)
#pragma unroll
                for (int rg = 0; rg < 4; ++rg)
                    m16 = fminf(m16, fmaf(-2.0f, acc[tc][tq][rg], c2r4[tc][rg]));
            if (m16 < v2[tq]) {        // something can enter the top-2
#pragma unroll
                for (int tc = 0; tc < 4; ++tc)
#pragma unroll
                    for (int rg = 0; rg < 4; ++rg) {
                        float y = fmaf(-2.0f, acc[tc][tq][rg], c2r4[tc][rg]);
                        if (y < v2[tq]) {
                            unsigned code = (unsigned)(ch * 128 + cw * 64 + tc * 16 + quad * 4 + rg);
                            if (y < v1[tq]) { v2[tq] = v1[tq]; v1[tq] = y; c1[tq] = code; }
                            else             v2[tq] = y;
                        }
                    }
            }
        }
    }

    // ---- exact slice-min per query, publish to global, fetch threshold
#pragma unroll
    for (int tq = 0; tq < 4; ++tq)
        atomicMin(&minU[qw * 64 + tq * 16 + l15], fmono(v1[tq]));
    __syncthreads();
    if (tid < 128) {
        unsigned mine = minU[tid];
        unsigned old  = atomicMin(&gminU[gq + tid], mine);   // publish + read
        gthr[tid] = fmono_inv(old < mine ? old : mine) + THR;
    }
    __syncthreads();

    // ---- push candidates: entry = (q<<11) | (type<<10) | payload
#pragma unroll
    for (int tq = 0; tq < 4; ++tq) {
        unsigned q = (unsigned)(qw * 64 + tq * 16 + l15);
        float g = gthr[q];
        if (v1[tq] <= g) {
            unsigned idx = atomicAdd(&qcnt, 1u);
            unsigned e = (q << 11) | c1[tq];
            if (idx < QCAP) queue[idx] = e;
            else rescore_one(n, m0 + (int)q, k0 + (int)c1[tq],
                             xex, contig, cb32, x2, c2, pmin);
        }
        if (v2[tq] <= g) {             // depth>=2 possible: rescan all 128
#pragma unroll
            for (int ch2 = 0; ch2 < 8; ++ch2) {
                unsigned idx = atomicAdd(&qcnt, 1u);
                unsigned e = (q << 11) | (1u << 10)
                           | ((unsigned)ch2 << 3) | ((unsigned)cw << 2) | (unsigned)quad;
                if (idx < QCAP) queue[idx] = e;
                else {                 // inline 16-code rescore (overflow)
                    for (int tc = 0; tc < 4; ++tc)
                        for (int rg = 0; rg < 4; ++rg)
                            rescore_one(n, m0 + (int)q,
                                        k0 + ch2 * 128 + cw * 64 + tc * 16 + quad * 4 + rg,
                                        xex, contig, cb32, x2, c2, pmin);
                }
            }
        }
    }
    __syncthreads();

    // ---- drain: exact fp32 rescore
    unsigned total = qcnt; if (total > QCAP) total = QCAP;
    for (unsigned i = tid; i < total; i += 256) {
        unsigned e = queue[i];
        unsigned q = e >> 11;
        if (e & (1u << 10)) {
            int ch2 = (int)((e >> 3) & 7u), cw2 = (int)((e >> 2) & 1u), qd = (int)(e & 3u);
            for (int tc = 0; tc < 4; ++tc)
                for (int rg = 0; rg < 4; ++rg)
                    rescore_one(n, m0 + (int)q,
                                k0 + ch2 * 128 + cw2 * 64 + tc * 16 + qd * 4 + rg,
                                xex, contig, cb32, x2, c2, pmin);
        } else {
            rescore_one(n, m0 + (int)q, k0 + (int)(e & 1023u),
                        xex, contig, cb32, x2, c2, pmin);
        }
    }

    // ---- arrival: last split-block for (n,qt) gathers inline
    __threadfence();
    __syncthreads();
    if (tid == 0)
        dflag = (atomicAdd(&gcnt[(n << 6) | qt], 1u) == NSPL - 1) ? 1 : 0;
    __syncthreads();
    if (!dflag) return;
    __threadfence();

    const int b = qt >> 3;
    const int t0g = (qt & 7) * 128;
    if (tid < 128) {
        unsigned long long e = atomicMin(&pmin[gq + tid], 0xFFFFFFFFFFFFFFFFull);
        int k = (int)(e & 0xFFFFFFFFull);
        kid[tid] = k;
        out[OUT_IDX_OFF + (b * NCBN + n) * TT + t0g + tid] = (float)k;
    }
    __syncthreads();

    const int q = tid & 127, hf = tid >> 7;
    const int k = kid[q];
    const float* cp = cb32 + ((size_t)n * KK + k) * DD + hf * 64;
    const float* xp; int st;
    if (contig) { xp = xex + ((size_t)n * MM + m0 + q) * DD + hf * 64; st = 1; }
    else        { xp = xex + ((size_t)(b * 256 + n * 128 + hf * 64)) * TT + t0g + q; st = TT; }
    float* ob = out + ((size_t)(b * 256 + n * 128 + hf * 64)) * TT + t0g + q;

    float lsum = 0.f;
#pragma unroll 4
    for (int j = 0; j < 64; ++j) {
        float qv = cp[j];
        float xv = xp[(size_t)j * st];
        ob[(size_t)j * TT] = qv;
        float e = xv - qv; lsum = fmaf(e, e, lsum);
    }

#pragma unroll
    for (int o = 32; o > 0; o >>= 1) lsum += __shfl_down(lsum, o, 64);
    if (lane == 0) wred[wave] = lsum;
    __syncthreads();
    if (tid == 0) {
        float tot = wred[0] + wred[1] + wred[2] + wred[3];
        atomicAdd(out + OUT_LOSS_OFF, tot * 2.384185791015625e-7f);  // 2^-22
    }
}

// ---------------------------------------------------------------------------
extern "C" void kernel_launch(void* const* d_in, const int* in_sizes, int n_in,
                              void* d_out, int out_size, void* d_ws, size_t ws_size,
                              hipStream_t stream) {
    (void)in_sizes; (void)n_in; (void)out_size;
    const float* x  = (const float*)d_in[0];
    const float* cb = (const float*)d_in[1];
    float* out = (float*)d_out;

    char* ws = (char*)d_ws;
    unsigned short* xbf = (unsigned short*)(ws);                       // 4 MiB
    unsigned short* cbf = (unsigned short*)(ws + (4u << 20));          // 4 MiB
    float* x2 = (float*)(ws + (8u << 20));                             // 64 KiB
    float* c2 = (float*)(ws + (8u << 20) + (64u << 10));               // 64 KiB
    unsigned long long* pmin =
        (unsigned long long*)(ws + (8u << 20) + (128u << 10));         // 128 KiB
    unsigned int* gminU =
        (unsigned int*)(ws + (8u << 20) + (256u << 10));               // 64 KiB
    unsigned int* gcnt =
        (unsigned int*)(ws + (8u << 20) + (320u << 10));               // 512 B
    float* x32t = (float*)(ws + (9u << 20));                           // 8 MiB

    const size_t need = (9u << 20) + (size_t)NCBN * MM * DD * 4;
    const int contig = (ws_size >= need) ? 1 : 0;
    const float* xex = contig ? x32t : x;

    prep_kernel<<<dim3(576), 256, 0, stream>>>(x, cb, xbf, cbf, x2, c2,
                                               x32t, contig, pmin, gminU, gcnt, out);
    screen_kernel<<<dim3(1024), 256, 0, stream>>>(xbf, cbf, c2, xex, contig,
                                                  cb, x2, gminU, pmin, gcnt, out);
}